// Round 1
// baseline (331.791 us; speedup 1.0000x reference)
//
#include <hip/hip_runtime.h>

// SceneContraction: means = contract(mean); cov_out = J cov J^T where
// J = jac(contract_gauss)(mean) for ||mean||>=1, else cov passthrough.
//
// Analytic Jacobian: with r=||x||, contract_gauss(x) = (2/r - 1/r^2) x = s*x,
//   ds/dx_j accumulation gives  J = s*I + c * x x^T,
//   s = (2r-1)/r^2 = (2 - 1/r)/r,   c = 2(1-r)/r^4.
// J is SYMMETRIC, so J C J^T = J C J (two 3x3 matmuls, ~54 FMA/sample).
//
// Memory-bound: 402.7 MB total HBM traffic -> ~64 us at 6.3 TB/s.
// Strategy: LDS staging so all global traffic is coalesced float4
// (AoS 3-/9-float records make direct per-thread loads strided).
// LDS compute-phase strides 3 and 9 are odd -> max 2 lanes/bank (free).

#define BLOCK 256

__global__ __launch_bounds__(BLOCK) void scene_contraction_kernel(
    const float* __restrict__ mean,
    const float* __restrict__ cov,
    float* __restrict__ out_mean,
    float* __restrict__ out_cov,
    int N)
{
    __shared__ float sm[BLOCK * 3];   // 3 KB
    __shared__ float sc[BLOCK * 9];   // 9 KB

    const int tid = threadIdx.x;
    const long long bs = (long long)blockIdx.x * BLOCK;   // first sample of block
    const bool full = (bs + BLOCK <= (long long)N);

    // ---- stage global -> LDS (coalesced float4 on the full-block path) ----
    if (full) {
        const float4* gm4 = (const float4*)(mean + bs * 3);   // 192 float4
        float4* sm4 = (float4*)sm;
        if (tid < 192) sm4[tid] = gm4[tid];

        const float4* gc4 = (const float4*)(cov + bs * 9);    // 576 float4
        float4* sc4 = (float4*)sc;
        sc4[tid]        = gc4[tid];
        sc4[tid + 256]  = gc4[tid + 256];
        if (tid < 64) sc4[tid + 512] = gc4[tid + 512];
    } else {
        const long long m_end = (long long)N * 3 - bs * 3;
        for (int i = tid; i < BLOCK * 3; i += BLOCK)
            if (i < m_end) sm[i] = mean[bs * 3 + i];
        const long long c_end = (long long)N * 9 - bs * 9;
        for (int i = tid; i < BLOCK * 9; i += BLOCK)
            if (i < c_end) sc[i] = cov[bs * 9 + i];
    }
    __syncthreads();

    // ---- per-thread compute (sample = bs + tid), in-place LDS update ----
    if (bs + tid < (long long)N) {
        const float x = sm[tid * 3 + 0];
        const float y = sm[tid * 3 + 1];
        const float z = sm[tid * 3 + 2];
        const float r2 = x * x + y * y + z * z;
        const float r = sqrtf(r2);

        if (r >= 1.0f) {
            const float inv  = 1.0f / r;
            const float s    = (2.0f - inv) * inv;        // 2/r - 1/r^2
            const float inv2 = inv * inv;
            const float cc   = 2.0f * (1.0f - r) * (inv2 * inv2);  // 2(1-r)/r^4

            // symmetric Jacobian
            const float j00 = fmaf(cc * x, x, s);
            const float j01 = cc * x * y;
            const float j02 = cc * x * z;
            const float j11 = fmaf(cc * y, y, s);
            const float j12 = cc * y * z;
            const float j22 = fmaf(cc * z, z, s);

            const float e0 = sc[tid * 9 + 0], e1 = sc[tid * 9 + 1], e2 = sc[tid * 9 + 2];
            const float e3 = sc[tid * 9 + 3], e4 = sc[tid * 9 + 4], e5 = sc[tid * 9 + 5];
            const float e6 = sc[tid * 9 + 6], e7 = sc[tid * 9 + 7], e8 = sc[tid * 9 + 8];

            // T = J * C
            const float t00 = j00 * e0 + j01 * e3 + j02 * e6;
            const float t01 = j00 * e1 + j01 * e4 + j02 * e7;
            const float t02 = j00 * e2 + j01 * e5 + j02 * e8;
            const float t10 = j01 * e0 + j11 * e3 + j12 * e6;
            const float t11 = j01 * e1 + j11 * e4 + j12 * e7;
            const float t12 = j01 * e2 + j11 * e5 + j12 * e8;
            const float t20 = j02 * e0 + j12 * e3 + j22 * e6;
            const float t21 = j02 * e1 + j12 * e4 + j22 * e7;
            const float t22 = j02 * e2 + j12 * e5 + j22 * e8;

            // O = T * J^T = T * J (J symmetric)
            sc[tid * 9 + 0] = t00 * j00 + t01 * j01 + t02 * j02;
            sc[tid * 9 + 1] = t00 * j01 + t01 * j11 + t02 * j12;
            sc[tid * 9 + 2] = t00 * j02 + t01 * j12 + t02 * j22;
            sc[tid * 9 + 3] = t10 * j00 + t11 * j01 + t12 * j02;
            sc[tid * 9 + 4] = t10 * j01 + t11 * j11 + t12 * j12;
            sc[tid * 9 + 5] = t10 * j02 + t11 * j12 + t12 * j22;
            sc[tid * 9 + 6] = t20 * j00 + t21 * j01 + t22 * j02;
            sc[tid * 9 + 7] = t20 * j01 + t21 * j11 + t22 * j12;
            sc[tid * 9 + 8] = t20 * j02 + t21 * j12 + t22 * j22;

            sm[tid * 3 + 0] = s * x;
            sm[tid * 3 + 1] = s * y;
            sm[tid * 3 + 2] = s * z;
        }
        // r < 1: means/cov pass through -> LDS already holds the answer.
    }
    __syncthreads();

    // ---- stage LDS -> global (coalesced float4 on the full-block path) ----
    if (full) {
        float4* om4 = (float4*)(out_mean + bs * 3);
        const float4* sm4 = (const float4*)sm;
        if (tid < 192) om4[tid] = sm4[tid];

        float4* oc4 = (float4*)(out_cov + bs * 9);
        const float4* sc4 = (const float4*)sc;
        oc4[tid]        = sc4[tid];
        oc4[tid + 256]  = sc4[tid + 256];
        if (tid < 64) oc4[tid + 512] = sc4[tid + 512];
    } else {
        const long long m_end = (long long)N * 3 - bs * 3;
        for (int i = tid; i < BLOCK * 3; i += BLOCK)
            if (i < m_end) out_mean[bs * 3 + i] = sm[i];
        const long long c_end = (long long)N * 9 - bs * 9;
        for (int i = tid; i < BLOCK * 9; i += BLOCK)
            if (i < c_end) out_cov[bs * 9 + i] = sc[i];
    }
}

extern "C" void kernel_launch(void* const* d_in, const int* in_sizes, int n_in,
                              void* d_out, int out_size, void* d_ws, size_t ws_size,
                              hipStream_t stream) {
    const float* mean = (const float*)d_in[0];
    const float* cov  = (const float*)d_in[1];
    float* out        = (float*)d_out;

    const int N = in_sizes[0] / 3;          // 4,194,304
    float* out_mean = out;
    float* out_cov  = out + (size_t)N * 3;

    const int blocks = (N + BLOCK - 1) / BLOCK;
    hipLaunchKernelGGL(scene_contraction_kernel, dim3(blocks), dim3(BLOCK), 0, stream,
                       mean, cov, out_mean, out_cov, N);
}